// Round 1
// baseline (717.894 us; speedup 1.0000x reference)
//
#include <hip/hip_runtime.h>
#include <math.h>

#define DIMS   256
#define KCODES 1024
#define NTOT   32768
#define TM     128
#define TN     128
#define TK     32
#define LSTR   132            // LDS row stride: 132*4=528 B, 16B-aligned, %32==4 -> <=2-way read conflicts
#define TAU    0.005f         // refinement margin (fp32 dist error ~1e-4 worst case; 50x safety)

// ---- workspace layout (float indices; ints share the view) ----
#define WS_COMMIT   0         // float atomic
#define WS_DECORR   1         // float atomic
#define WS_FLAGCNT  2         // int atomic
#define WS_COLSUM   16        // float[256]
#define WS_COLSQ    272       // float[256]
#define WS_WSQ      1024      // float[1024]
#define WS_XSQ      2048      // float[32768]
#define WS_FLAGLIST 34816     // int[32768]
// zero-init needed: floats [0,528) -> memset first 4096 bytes (wsq starts at byte 4096, untouched)

// ---- output layout (floats) ----
#define OUT_Q    0
#define OUT_IDX  8388608
#define OUT_SCAL 8421376

// ---------- row sum-of-squares: one wave per row ----------
__global__ __launch_bounds__(256) void rowsq_kernel(const float* __restrict__ A,
                                                    float* __restrict__ out, int rows) {
  int wave = threadIdx.x >> 6, lane = threadIdx.x & 63;
  int row = blockIdx.x * 4 + wave;
  if (row >= rows) return;
  float4 v = ((const float4*)(A + (size_t)row * DIMS))[lane];
  float s = v.x * v.x + v.y * v.y + v.z * v.z + v.w * v.w;
  #pragma unroll
  for (int m = 32; m >= 1; m >>= 1) s += __shfl_xor(s, m);
  if (lane == 0) out[row] = s;
}

// ---------- per-column sum / sumsq of W (for variance + mean) ----------
__global__ __launch_bounds__(256) void colstats_kernel(const float* __restrict__ W, float* ws) {
  int d = threadIdx.x;
  int r0 = blockIdx.x * 128;
  float s = 0.f, sq = 0.f;
  #pragma unroll 8
  for (int k = 0; k < 128; k++) {
    float v = W[(size_t)(r0 + k) * DIMS + d];
    s += v;
    sq = fmaf(v, v, sq);
  }
  atomicAdd(&ws[WS_COLSUM + d], s);
  atomicAdd(&ws[WS_COLSQ + d], sq);
}

// ---------- pass1: tiled fp32 distance GEMM + running argmin(+2nd) + gather + commitment ----------
__global__ __launch_bounds__(256) void pass1_kernel(const float* __restrict__ X,
                                                    const float* __restrict__ W,
                                                    float* __restrict__ outQ,
                                                    float* __restrict__ outIdx,
                                                    float* ws) {
  __shared__ float As[TK][LSTR];
  __shared__ float Bs[TK][LSTR];
  __shared__ float wsqs[TN];
  __shared__ int idx_s[TM];
  const float* xsq = ws + WS_XSQ;
  const float* wsq = ws + WS_WSQ;
  int tid = threadIdx.x;
  int tx = tid & 15, ty = tid >> 4;
  int rowBase = blockIdx.x * TM;
  int s_row = tid >> 3;  // 0..31
  int s_c8 = tid & 7;    // 0..7 (which float4 along k)

  float bestD[8], best2[8];
  int bestI[8];
  #pragma unroll
  for (int i = 0; i < 8; i++) { bestD[i] = 3.0e38f; best2[i] = 3.0e38f; bestI[i] = 0; }

  for (int ct = 0; ct < KCODES / TN; ++ct) {
    int cb = ct * TN;
    __syncthreads();  // protect wsqs vs previous tile's epilogue readers
    if (tid < TN) wsqs[tid] = wsq[cb + tid];
    float acc[8][8];
    #pragma unroll
    for (int i = 0; i < 8; i++)
      #pragma unroll
      for (int j = 0; j < 8; j++) acc[i][j] = 0.f;

    for (int kt = 0; kt < DIMS; kt += TK) {
      float4 av[4], bv[4];
      #pragma unroll
      for (int c = 0; c < 4; c++) {
        int r = s_row + 32 * c;
        av[c] = *(const float4*)&X[(size_t)(rowBase + r) * DIMS + kt + s_c8 * 4];
        bv[c] = *(const float4*)&W[(size_t)(cb + r) * DIMS + kt + s_c8 * 4];
      }
      __syncthreads();  // previous chunk's LDS reads done
      #pragma unroll
      for (int c = 0; c < 4; c++) {
        int r = s_row + 32 * c;
        int kb = s_c8 * 4;
        As[kb + 0][r] = av[c].x; As[kb + 1][r] = av[c].y;
        As[kb + 2][r] = av[c].z; As[kb + 3][r] = av[c].w;
        Bs[kb + 0][r] = bv[c].x; Bs[kb + 1][r] = bv[c].y;
        Bs[kb + 2][r] = bv[c].z; Bs[kb + 3][r] = bv[c].w;
      }
      __syncthreads();
      #pragma unroll 8
      for (int k = 0; k < TK; k++) {
        float4 a0 = *(const float4*)&As[k][ty * 4];
        float4 a1 = *(const float4*)&As[k][64 + ty * 4];
        float4 b0 = *(const float4*)&Bs[k][tx * 4];
        float4 b1 = *(const float4*)&Bs[k][64 + tx * 4];
        float aa[8] = {a0.x, a0.y, a0.z, a0.w, a1.x, a1.y, a1.z, a1.w};
        float bb[8] = {b0.x, b0.y, b0.z, b0.w, b1.x, b1.y, b1.z, b1.w};
        #pragma unroll
        for (int i = 0; i < 8; i++)
          #pragma unroll
          for (int j = 0; j < 8; j++) acc[i][j] = fmaf(aa[i], bb[j], acc[i][j]);
      }
    }
    // epilogue: d' = wsq - 2*s ; track best + second-best per sample row
    #pragma unroll
    for (int i = 0; i < 8; i++) {
      float d1 = 3.0e38f, d2 = 3.0e38f;
      int i1 = 0;
      #pragma unroll
      for (int j = 0; j < 8; j++) {
        int n = tx * 4 + (j & 3) + ((j >> 2) << 6);
        float d = wsqs[n] - 2.0f * acc[i][j];
        int g = cb + n;  // ascending in j -> ties keep first (smaller idx)
        if (d < d1) { d2 = d1; d1 = d; i1 = g; }
        else if (d < d2) d2 = d;
      }
      #pragma unroll
      for (int m = 1; m < 16; m <<= 1) {
        float od1 = __shfl_xor(d1, m);
        int oi1 = __shfl_xor(i1, m);
        float od2 = __shfl_xor(d2, m);
        if (od1 < d1 || (od1 == d1 && oi1 < i1)) {
          d2 = fminf(d1, fminf(d2, od2));
          d1 = od1; i1 = oi1;
        } else {
          d2 = fminf(od1, fminf(d2, od2));
        }
      }
      if (d1 < bestD[i] || (d1 == bestD[i] && i1 < bestI[i])) {
        best2[i] = fminf(bestD[i], fminf(best2[i], d2));
        bestD[i] = d1; bestI[i] = i1;
      } else {
        best2[i] = fminf(d1, fminf(best2[i], d2));
      }
    }
  }

  if (tx == 0) {
    float partial = 0.f;
    int* wsI = (int*)ws;
    #pragma unroll
    for (int i = 0; i < 8; i++) {
      int m = ty * 4 + (i & 3) + ((i >> 2) << 6);
      int gr = rowBase + m;
      idx_s[m] = bestI[i];
      outIdx[gr] = (float)bestI[i];
      partial += xsq[gr] + bestD[i];  // full min squared distance
      if (best2[i] - bestD[i] < TAU) {
        int p = atomicAdd(&wsI[WS_FLAGCNT], 1);
        wsI[WS_FLAGLIST + p] = gr;
      }
    }
    atomicAdd(&ws[WS_COMMIT], partial);
  }
  __syncthreads();
  // quant gather: 128 rows x 64 float4
  #pragma unroll
  for (int c = 0; c < 32; c++) {
    int lin = tid + c * 256;
    int row = lin >> 6, col4 = lin & 63;
    float4 v = *(const float4*)&W[(size_t)idx_s[row] * DIMS + col4 * 4];
    *(float4*)&outQ[(size_t)(rowBase + row) * DIMS + col4 * 4] = v;
  }
}

// ---------- decorrelation: block i computes cov(i, :) ----------
__global__ __launch_bounds__(256) void cov_kernel(const float* __restrict__ W, float* ws) {
  __shared__ float wi[KCODES];
  int i = blockIdx.x, j = threadIdx.x;
  for (int k = threadIdx.x; k < KCODES; k += 256) wi[k] = W[(size_t)k * DIMS + i];
  __syncthreads();
  const float inv = 1.0f / 1024.0f;
  float mi = ws[WS_COLSUM + i] * inv, mj = ws[WS_COLSUM + j] * inv;
  float dot = 0.f;
  #pragma unroll 8
  for (int k = 0; k < KCODES; k++) dot = fmaf(wi[k], W[(size_t)k * DIMS + j], dot);
  float c = dot * inv - mi * mj;  // cov_ij = dot/K - m_i*m_j
  float val = (i == j) ? 0.0f : c * c;
  #pragma unroll
  for (int m = 32; m >= 1; m >>= 1) val += __shfl_xor(val, m);
  if ((threadIdx.x & 63) == 0) atomicAdd(&ws[WS_DECORR], val);
}

// ---------- fp64 refinement of near-tie rows ----------
__global__ __launch_bounds__(256) void refine_kernel(const float* __restrict__ X,
                                                     const float* __restrict__ W,
                                                     float* __restrict__ outQ,
                                                     float* __restrict__ outIdx, float* ws) {
  __shared__ float xrow[DIMS];
  __shared__ double bd[4];
  __shared__ int bi[4];
  __shared__ int chosen;
  const int* wsI = (const int*)ws;
  int cnt = wsI[WS_FLAGCNT];
  const int* list = wsI + WS_FLAGLIST;
  int tid = threadIdx.x, wave = tid >> 6, lane = tid & 63;
  for (int f = blockIdx.x; f < cnt; f += gridDim.x) {
    int row = list[f];
    __syncthreads();
    if (tid < 64) ((float4*)xrow)[tid] = ((const float4*)(X + (size_t)row * DIMS))[tid];
    __syncthreads();
    float4 xv = ((const float4*)xrow)[lane];
    double d1 = 1e300;
    int i1 = 0;
    for (int k = wave; k < KCODES; k += 4) {
      float4 wv = ((const float4*)(W + (size_t)k * DIMS))[lane];
      double dx = (double)xv.x - (double)wv.x;
      double dy = (double)xv.y - (double)wv.y;
      double dz = (double)xv.z - (double)wv.z;
      double dw = (double)xv.w - (double)wv.w;
      double s = dx * dx + dy * dy + dz * dz + dw * dw;
      #pragma unroll
      for (int m = 32; m >= 1; m >>= 1) s += __shfl_xor(s, m);
      if (s < d1) { d1 = s; i1 = k; }  // k ascending within wave -> first kept on tie
    }
    if (lane == 0) { bd[wave] = d1; bi[wave] = i1; }
    __syncthreads();
    if (tid == 0) {
      double b = bd[0]; int ix = bi[0];
      #pragma unroll
      for (int w = 1; w < 4; w++)
        if (bd[w] < b || (bd[w] == b && bi[w] < ix)) { b = bd[w]; ix = bi[w]; }
      chosen = ix;
      outIdx[row] = (float)ix;
    }
    __syncthreads();
    int ix = chosen;
    if (tid < 64)
      ((float4*)(outQ + (size_t)row * DIMS))[tid] = ((const float4*)(W + (size_t)ix * DIMS))[tid];
  }
}

// ---------- scalar losses ----------
__global__ __launch_bounds__(256) void finalize_kernel(const float* __restrict__ U, float* ws,
                                                       float* __restrict__ out) {
  __shared__ float red[256];
  int tid = threadIdx.x;
  float s = 0.f;
  for (int e = tid; e < KCODES; e += 256) s += U[e] + 1e-5f;
  red[tid] = s;
  __syncthreads();
  for (int st = 128; st >= 1; st >>= 1) {
    if (tid < st) red[tid] += red[tid + st];
    __syncthreads();
  }
  float S = red[0];
  __syncthreads();
  float denom = fmaxf(S, 1e-5f * 1024.0f);
  float h = 0.f;
  for (int e = tid; e < KCODES; e += 256) {
    float p = (U[e] + 1e-5f) / denom;
    h += p * logf(p + 1e-5f);
  }
  red[tid] = h;
  __syncthreads();
  for (int st = 128; st >= 1; st >>= 1) {
    if (tid < st) red[tid] += red[tid + st];
    __syncthreads();
  }
  float H = -red[0] / 6.93147180559945f;  // ln(1024)
  __syncthreads();
  float m = ws[WS_COLSUM + tid] * (1.0f / 1024.0f);
  float var = ws[WS_COLSQ + tid] * (1.0f / 1024.0f) - m * m;
  float r = 0.05f - var;
  red[tid] = r > 0.f ? r : 0.f;
  __syncthreads();
  for (int st = 128; st >= 1; st >>= 1) {
    if (tid < st) red[tid] += red[tid + st];
    __syncthreads();
  }
  if (tid == 0) {
    float varloss = 1e-3f * (red[0] / 256.0f);
    float gap = H < 0.5f ? (0.5f - H) : (H > 0.9f ? (H - 0.9f) : 0.0f);
    float entloss = 0.1f * gap * gap;
    float commit = 0.25f * ws[WS_COMMIT] / 8388608.0f;
    float dec = 1e-3f * ws[WS_DECORR] / 65536.0f;
    float* sc = out + OUT_SCAL;
    sc[0] = commit + entloss + varloss + dec;
    sc[1] = commit;
    sc[2] = entloss;
    sc[3] = varloss;
    sc[4] = dec;
    sc[5] = H;
  }
}

extern "C" void kernel_launch(void* const* d_in, const int* in_sizes, int n_in, void* d_out,
                              int out_size, void* d_ws, size_t ws_size, hipStream_t stream) {
  const float* X = (const float*)d_in[0];
  const float* W = (const float*)d_in[1];
  const float* U = (const float*)d_in[2];
  float* out = (float*)d_out;
  float* ws = (float*)d_ws;

  hipMemsetAsync(d_ws, 0, 4096, stream);
  rowsq_kernel<<<NTOT / 4, 256, 0, stream>>>(X, ws + WS_XSQ, NTOT);
  rowsq_kernel<<<KCODES / 4, 256, 0, stream>>>(W, ws + WS_WSQ, KCODES);
  colstats_kernel<<<8, 256, 0, stream>>>(W, ws);
  pass1_kernel<<<NTOT / TM, 256, 0, stream>>>(X, W, out + OUT_Q, out + OUT_IDX, ws);
  cov_kernel<<<256, 256, 0, stream>>>(W, ws);
  refine_kernel<<<64, 256, 0, stream>>>(X, W, out + OUT_Q, out + OUT_IDX, ws);
  finalize_kernel<<<1, 256, 0, stream>>>(U, ws, out);
}

// Round 2
// 326.140 us; speedup vs baseline: 2.2012x; 2.2012x over previous
//
#include <hip/hip_runtime.h>
#include <math.h>

#define DIMS   256
#define KCODES 1024
#define NTOT   32768
#define TM     128
#define TN     128
#define LSTR   40             // LDS tile k-stride in bf16 elems (80 B: 16B-aligned, uniform banks)
#define TAU    0.002f         // refine margin; bf16-split worst-case dist-cmp error < 1e-3

typedef __bf16 bf16x8 __attribute__((ext_vector_type(8)));
typedef float  f32x4  __attribute__((ext_vector_type(4)));

// ---- workspace layout (float indices; int views share) ----
#define WS_COMMIT   0          // float atomic
#define WS_FLAGCNT  1          // int atomic
#define WS_COLSUM   16         // float[256]
#define WS_COLSQ    272        // float[256]
#define WS_COVBUF   1024       // float[65536] (atomic partial dots)
// ---- zero region ends at 66560 floats = 266240 bytes ----
#define WS_WSQ      66560      // float[1024]
#define WS_XSQ      67584      // float[32768]
#define WS_IDXF     100352     // int[32768]
#define WS_FLAGS    133120     // int[32768]
#define WS_CAND1    165888     // float[8*32768]
#define WS_CAND2    428032     // float[8*32768]
#define WS_CANDI    690176     // int[8*32768]

// ---- output layout (floats) ----
#define OUT_Q    0
#define OUT_IDX  8388608
#define OUT_SCAL 8421376

// ---------- row sum-of-squares: one wave per row ----------
__global__ __launch_bounds__(256) void rowsq_kernel(const float* __restrict__ A,
                                                    float* __restrict__ out, int rows) {
  int wave = threadIdx.x >> 6, lane = threadIdx.x & 63;
  int row = blockIdx.x * 4 + wave;
  if (row >= rows) return;
  float4 v = ((const float4*)(A + (size_t)row * DIMS))[lane];
  float s = v.x * v.x + v.y * v.y + v.z * v.z + v.w * v.w;
  #pragma unroll
  for (int m = 32; m >= 1; m >>= 1) s += __shfl_xor(s, m);
  if (lane == 0) out[row] = s;
}

// ---------- per-column sum / sumsq of W ----------
__global__ __launch_bounds__(256) void colstats_kernel(const float* __restrict__ W, float* ws) {
  int d = threadIdx.x;
  int r0 = blockIdx.x * 32;
  float s = 0.f, sq = 0.f;
  #pragma unroll 8
  for (int k = 0; k < 32; k++) {
    float v = W[(size_t)(r0 + k) * DIMS + d];
    s += v;
    sq = fmaf(v, v, sq);
  }
  atomicAdd(&ws[WS_COLSUM + d], s);
  atomicAdd(&ws[WS_COLSQ + d], sq);
}

// ---------- pass1: bf16-split MFMA distance GEMM (3-term), per-block argmin candidates ----------
// grid (8 ntile, 256 mtile), 256 threads = 4 waves in 2x2
__global__ __launch_bounds__(256) void pass1_kernel(const float* __restrict__ X,
                                                    const float* __restrict__ W,
                                                    float* ws) {
  __shared__ __bf16 Ah[TM * LSTR];
  __shared__ __bf16 Al[TM * LSTR];
  __shared__ __bf16 Bh[TN * LSTR];
  __shared__ __bf16 Bl[TN * LSTR];
  __shared__ float wsqs[TN];
  __shared__ float d1L[TM * 2];
  __shared__ float d2L[TM * 2];
  __shared__ int   i1L[TM * 2];

  const float* wsq = ws + WS_WSQ;
  int tid = threadIdx.x;
  int lane = tid & 63, wave = tid >> 6;
  int waveM = wave >> 1, waveN = wave & 1;
  int quad = lane >> 4, col = lane & 15;
  int bn = blockIdx.x, bm = blockIdx.y;
  int rowBase = bm * TM, cb = bn * TN;

  if (tid < TN) wsqs[tid] = wsq[cb + tid];

  f32x4 acc[4][4];
  #pragma unroll
  for (int i = 0; i < 4; i++)
    #pragma unroll
    for (int j = 0; j < 4; j++) acc[i][j] = (f32x4){0.f, 0.f, 0.f, 0.f};

  // staging assignment: chunk id = tid + 256*c; row = id>>2 (0..127), c8 = id&3 (8-float cols)
  for (int kt = 0; kt < DIMS; kt += 32) {
    float4 au[2], av[2], bu[2], bv[2];
    #pragma unroll
    for (int c = 0; c < 2; c++) {
      int id = tid + 256 * c;
      int row = id >> 2, c8 = id & 3;
      const float* sa = X + (size_t)(rowBase + row) * DIMS + kt + c8 * 8;
      const float* sb = W + (size_t)(cb + row) * DIMS + kt + c8 * 8;
      au[c] = *(const float4*)sa;  av[c] = *(const float4*)(sa + 4);
      bu[c] = *(const float4*)sb;  bv[c] = *(const float4*)(sb + 4);
    }
    __syncthreads();  // previous tile's LDS reads complete
    #pragma unroll
    for (int c = 0; c < 2; c++) {
      int id = tid + 256 * c;
      int row = id >> 2, c8 = id & 3;
      float f[8] = {au[c].x, au[c].y, au[c].z, au[c].w, av[c].x, av[c].y, av[c].z, av[c].w};
      bf16x8 h, l;
      #pragma unroll
      for (int e = 0; e < 8; e++) {
        __bf16 hh = (__bf16)f[e];
        h[e] = hh;
        l[e] = (__bf16)(f[e] - (float)hh);
      }
      *(bf16x8*)&Ah[row * LSTR + c8 * 8] = h;
      *(bf16x8*)&Al[row * LSTR + c8 * 8] = l;
      float g[8] = {bu[c].x, bu[c].y, bu[c].z, bu[c].w, bv[c].x, bv[c].y, bv[c].z, bv[c].w};
      bf16x8 h2, l2;
      #pragma unroll
      for (int e = 0; e < 8; e++) {
        __bf16 hh = (__bf16)g[e];
        h2[e] = hh;
        l2[e] = (__bf16)(g[e] - (float)hh);
      }
      *(bf16x8*)&Bh[row * LSTR + c8 * 8] = h2;
      *(bf16x8*)&Bl[row * LSTR + c8 * 8] = l2;
    }
    __syncthreads();
    // fragment reads: A[m = lane&15][k = quad*8+j], B[n = lane&15][k = quad*8+j]
    bf16x8 ah[4], al[4];
    #pragma unroll
    for (int mt = 0; mt < 4; mt++) {
      int r = waveM * 64 + mt * 16 + col;
      ah[mt] = *(const bf16x8*)&Ah[r * LSTR + quad * 8];
      al[mt] = *(const bf16x8*)&Al[r * LSTR + quad * 8];
    }
    #pragma unroll
    for (int nt = 0; nt < 4; nt++) {
      int r = waveN * 64 + nt * 16 + col;
      bf16x8 bh = *(const bf16x8*)&Bh[r * LSTR + quad * 8];
      bf16x8 bl = *(const bf16x8*)&Bl[r * LSTR + quad * 8];
      #pragma unroll
      for (int mt = 0; mt < 4; mt++) {
        acc[mt][nt] = __builtin_amdgcn_mfma_f32_16x16x32_bf16(ah[mt], bh, acc[mt][nt], 0, 0, 0);
        acc[mt][nt] = __builtin_amdgcn_mfma_f32_16x16x32_bf16(ah[mt], bl, acc[mt][nt], 0, 0, 0);
        acc[mt][nt] = __builtin_amdgcn_mfma_f32_16x16x32_bf16(al[mt], bh, acc[mt][nt], 0, 0, 0);
      }
    }
  }

  // epilogue: per-row (best, 2nd, idx) over this block's 128 codes
  // C layout: row = quad*4 + reg, col = lane&15
  #pragma unroll
  for (int mt = 0; mt < 4; mt++) {
    #pragma unroll
    for (int r = 0; r < 4; r++) {
      float d1 = 3.0e38f, d2 = 3.0e38f;
      int i1 = 0;
      #pragma unroll
      for (int nt = 0; nt < 4; nt++) {
        int lc = waveN * 64 + nt * 16 + col;
        float d = wsqs[lc] - 2.0f * acc[mt][nt][r];
        int g = cb + lc;
        if (d < d1) { d2 = d1; d1 = d; i1 = g; }
        else if (d < d2) d2 = d;
      }
      #pragma unroll
      for (int m = 1; m < 16; m <<= 1) {
        float od1 = __shfl_xor(d1, m);
        int oi1 = __shfl_xor(i1, m);
        float od2 = __shfl_xor(d2, m);
        if (od1 < d1 || (od1 == d1 && oi1 < i1)) {
          d2 = fminf(d1, fminf(d2, od2));
          d1 = od1; i1 = oi1;
        } else {
          d2 = fminf(od1, fminf(d2, od2));
        }
      }
      if (col == 0) {
        int lr = waveM * 64 + mt * 16 + quad * 4 + r;
        d1L[lr * 2 + waveN] = d1;
        d2L[lr * 2 + waveN] = d2;
        i1L[lr * 2 + waveN] = i1;
      }
    }
  }
  __syncthreads();
  if (tid < TM) {
    float a1 = d1L[tid * 2], a2 = d2L[tid * 2];
    int ai = i1L[tid * 2];
    float b1 = d1L[tid * 2 + 1], b2 = d2L[tid * 2 + 1];
    int bi = i1L[tid * 2 + 1];
    float m1, m2; int mi;
    if (b1 < a1 || (b1 == a1 && bi < ai)) { m1 = b1; mi = bi; m2 = fminf(a1, b2); }
    else { m1 = a1; mi = ai; m2 = fminf(b1, a2); }
    int o = bn * NTOT + rowBase + tid;
    ws[WS_CAND1 + o] = m1;
    ws[WS_CAND2 + o] = m2;
    ((int*)ws)[WS_CANDI + o] = mi;
  }
}

// ---------- pass2: merge 8 candidate sets per row; idx, commit, flags ----------
__global__ __launch_bounds__(256) void pass2_kernel(float* __restrict__ outIdx, float* ws) {
  int row = blockIdx.x * 256 + threadIdx.x;
  const float* c1 = ws + WS_CAND1;
  const float* c2 = ws + WS_CAND2;
  const int* ci = (const int*)ws + WS_CANDI;
  float m1 = 3.0e38f, m2 = 3.0e38f;
  int mi = 0;
  #pragma unroll
  for (int b = 0; b < 8; b++) {
    int o = b * NTOT + row;
    float b1 = c1[o], b2 = c2[o];
    int bi = ci[o];
    if (b1 < m1 || (b1 == m1 && bi < mi)) { m2 = fminf(m1, b2); m1 = b1; mi = bi; }
    else { m2 = fminf(m2, b1); }
  }
  outIdx[row] = (float)mi;
  ((int*)ws)[WS_IDXF + row] = mi;
  int* wsI = (int*)ws;
  if (m2 - m1 < TAU) {
    int p = atomicAdd(&wsI[WS_FLAGCNT], 1);
    wsI[WS_FLAGS + p] = row;
  }
  float partial = ws[WS_XSQ + row] + m1;
  #pragma unroll
  for (int m = 32; m >= 1; m >>= 1) partial += __shfl_xor(partial, m);
  if ((threadIdx.x & 63) == 0) atomicAdd(&ws[WS_COMMIT], partial);
}

// ---------- gather quant rows ----------
__global__ __launch_bounds__(256) void gather_kernel(const float* __restrict__ W,
                                                     float* __restrict__ outQ, const float* ws) {
  int wave = threadIdx.x >> 6, lane = threadIdx.x & 63;
  int row = blockIdx.x * 4 + wave;
  int idx = ((const int*)ws)[WS_IDXF + row];
  float4 v = ((const float4*)(W + (size_t)idx * DIMS))[lane];
  ((float4*)(outQ + (size_t)row * DIMS))[lane] = v;
}

// ---------- cov partial dots: grid (4 kq, 256 i) ----------
__global__ __launch_bounds__(256) void cov1_kernel(const float* __restrict__ W, float* ws) {
  __shared__ float wi_s[256];
  int kq = blockIdx.x, i = blockIdx.y, j = threadIdx.x;
  int k0 = kq * 256;
  wi_s[j] = W[(size_t)(k0 + j) * DIMS + i];
  __syncthreads();
  float p = 0.f;
  #pragma unroll 8
  for (int k = 0; k < 256; k++) p = fmaf(wi_s[k], W[(size_t)(k0 + k) * DIMS + j], p);
  atomicAdd(&ws[WS_COVBUF + i * 256 + j], p);
}

// ---------- f64 refinement of near-tie rows: one block per flagged row ----------
__global__ __launch_bounds__(256) void refine_kernel(const float* __restrict__ X,
                                                     const float* __restrict__ W,
                                                     float* __restrict__ outQ,
                                                     float* __restrict__ outIdx, float* ws) {
  __shared__ float xs[DIMS];
  __shared__ double dm[256];
  __shared__ int im[256];
  __shared__ int chosen;
  const int* wsI = (const int*)ws;
  int cnt = wsI[WS_FLAGCNT];
  const int* list = wsI + WS_FLAGS;
  int tid = threadIdx.x;
  for (int f = blockIdx.x; f < cnt; f += gridDim.x) {
    int row = list[f];
    __syncthreads();
    if (tid < 64) ((float4*)xs)[tid] = ((const float4*)(X + (size_t)row * DIMS))[tid];
    __syncthreads();
    double bd = 1.0e300;
    int bi = 0;
    for (int j = 0; j < 4; j++) {
      int c = tid + 256 * j;
      double a0 = 0.0, a1 = 0.0, a2 = 0.0, a3 = 0.0;
      const float* wr = W + (size_t)c * DIMS;
      #pragma unroll 4
      for (int d4 = 0; d4 < 64; d4++) {
        float4 w = ((const float4*)wr)[d4];
        float4 x = ((const float4*)xs)[d4];
        double e0 = (double)x.x - (double)w.x;
        double e1 = (double)x.y - (double)w.y;
        double e2 = (double)x.z - (double)w.z;
        double e3 = (double)x.w - (double)w.w;
        a0 += e0 * e0; a1 += e1 * e1; a2 += e2 * e2; a3 += e3 * e3;
      }
      double s = (a0 + a1) + (a2 + a3);
      if (s < bd) { bd = s; bi = c; }
    }
    dm[tid] = bd; im[tid] = bi;
    __syncthreads();
    for (int st = 128; st >= 1; st >>= 1) {
      if (tid < st) {
        if (dm[tid + st] < dm[tid] || (dm[tid + st] == dm[tid] && im[tid + st] < im[tid])) {
          dm[tid] = dm[tid + st]; im[tid] = im[tid + st];
        }
      }
      __syncthreads();
    }
    if (tid == 0) { chosen = im[0]; outIdx[row] = (float)im[0]; }
    __syncthreads();
    int ix = chosen;
    if (tid < 64)
      ((float4*)(outQ + (size_t)row * DIMS))[tid] = ((const float4*)(W + (size_t)ix * DIMS))[tid];
  }
}

// ---------- scalar losses ----------
__global__ __launch_bounds__(256) void finalize_kernel(const float* __restrict__ U, float* ws,
                                                       float* __restrict__ out) {
  __shared__ float red[256];
  __shared__ float mean_s[256];
  int tid = threadIdx.x;
  float s = 0.f;
  for (int e = tid; e < KCODES; e += 256) s += U[e] + 1e-5f;
  red[tid] = s;
  __syncthreads();
  for (int st = 128; st >= 1; st >>= 1) {
    if (tid < st) red[tid] += red[tid + st];
    __syncthreads();
  }
  float S = red[0];
  __syncthreads();
  float denom = fmaxf(S, 1e-5f * 1024.0f);
  float h = 0.f;
  for (int e = tid; e < KCODES; e += 256) {
    float p = (U[e] + 1e-5f) / denom;
    h += p * logf(p + 1e-5f);
  }
  red[tid] = h;
  __syncthreads();
  for (int st = 128; st >= 1; st >>= 1) {
    if (tid < st) red[tid] += red[tid + st];
    __syncthreads();
  }
  float H = -red[0] / 6.93147180559945f;  // ln(1024)
  __syncthreads();
  // variance floor
  float m = ws[WS_COLSUM + tid] * (1.0f / 1024.0f);
  mean_s[tid] = m;
  float var = ws[WS_COLSQ + tid] * (1.0f / 1024.0f) - m * m;
  float r = 0.05f - var;
  red[tid] = r > 0.f ? r : 0.f;
  __syncthreads();
  for (int st = 128; st >= 1; st >>= 1) {
    if (tid < st) red[tid] += red[tid + st];
    __syncthreads();
  }
  float varred = red[0];
  __syncthreads();
  // decorrelation from covbuf
  float dsum = 0.f;
  for (int t = 0; t < 256; t++) {
    float c = ws[WS_COVBUF + t * 256 + tid] * (1.0f / 1024.0f) - mean_s[t] * mean_s[tid];
    if (t != tid) dsum = fmaf(c, c, dsum);
  }
  red[tid] = dsum;
  __syncthreads();
  for (int st = 128; st >= 1; st >>= 1) {
    if (tid < st) red[tid] += red[tid + st];
    __syncthreads();
  }
  if (tid == 0) {
    float varloss = 1e-3f * (varred / 256.0f);
    float gap = H < 0.5f ? (0.5f - H) : (H > 0.9f ? (H - 0.9f) : 0.0f);
    float entloss = 0.1f * gap * gap;
    float commit = 0.25f * ws[WS_COMMIT] / 8388608.0f;
    float dec = 1e-3f * red[0] / 65536.0f;
    float* sc = out + OUT_SCAL;
    sc[0] = commit + entloss + varloss + dec;
    sc[1] = commit;
    sc[2] = entloss;
    sc[3] = varloss;
    sc[4] = dec;
    sc[5] = H;
  }
}

extern "C" void kernel_launch(void* const* d_in, const int* in_sizes, int n_in, void* d_out,
                              int out_size, void* d_ws, size_t ws_size, hipStream_t stream) {
  const float* X = (const float*)d_in[0];
  const float* W = (const float*)d_in[1];
  const float* U = (const float*)d_in[2];
  float* out = (float*)d_out;
  float* ws = (float*)d_ws;

  hipMemsetAsync(d_ws, 0, 266240, stream);
  rowsq_kernel<<<KCODES / 4, 256, 0, stream>>>(W, ws + WS_WSQ, KCODES);
  rowsq_kernel<<<NTOT / 4, 256, 0, stream>>>(X, ws + WS_XSQ, NTOT);
  colstats_kernel<<<32, 256, 0, stream>>>(W, ws);
  pass1_kernel<<<dim3(8, 256), 256, 0, stream>>>(X, W, ws);
  pass2_kernel<<<NTOT / 256, 256, 0, stream>>>(out + OUT_IDX, ws);
  gather_kernel<<<NTOT / 4, 256, 0, stream>>>(W, out + OUT_Q, ws);
  refine_kernel<<<512, 256, 0, stream>>>(X, W, out + OUT_Q, out + OUT_IDX, ws);
  cov1_kernel<<<dim3(4, 256), 256, 0, stream>>>(W, ws);
  finalize_kernel<<<1, 256, 0, stream>>>(U, ws, out);
}

// Round 3
// 256.808 us; speedup vs baseline: 2.7954x; 1.2700x over previous
//
#include <hip/hip_runtime.h>
#include <math.h>

#define DIMS   256
#define KCODES 1024
#define NTOT   32768
#define TAU    0.002f

typedef __bf16 bf16x8 __attribute__((ext_vector_type(8)));
typedef float  f32x4  __attribute__((ext_vector_type(4)));

typedef const void __attribute__((address_space(1))) glb_cv;
typedef void __attribute__((address_space(3))) lds_v;

__device__ __forceinline__ void gload_lds16(const void* g, void* l) {
  __builtin_amdgcn_global_load_lds((glb_cv*)g, (lds_v*)l, 16, 0, 0);
}

// ---- workspace layout (float indices; int views share) ----
#define WS_COMMIT   0          // float atomic
#define WS_FLAGCNT  1          // int atomic
#define WS_DECORR   2          // float atomic
#define WS_COLSUM   16         // float[256]
#define WS_COLSQ    272        // float[256]
// zero region: first 2112 bytes
#define WS_WSQ      1024       // float[1024]
#define WS_XSQ      2048       // float[32768]
#define WS_FLAGS    34816      // int[32768]
#define WS_CAND1    67584      // float[8*32768]
#define WS_CAND2    329728     // float[8*32768]
#define WS_CANDI    591872     // int[8*32768]
#define WS_WP       854016     // bf16[1024*256*2] = 1 MB

// ---- output layout (floats) ----
#define OUT_Q    0
#define OUT_IDX  8388608
#define OUT_SCAL 8421376

// ---------- pack fp32 -> swizzled hi/lo bf16 tiles + row sumsq ----------
// Tile layout (bf16 elems): [(rb*8+kt)*8192 + row128*64 + p*8 + e]
// slot p holds logical s = p ^ (row&7); s<4: hi of k-group s; s>=4: lo of k-group s-4.
// Block = 64 rows, thread = (row_l = tid>>2, kg = tid&3), loops kt 0..7.
__global__ __launch_bounds__(256) void pack_kernel(const float* __restrict__ src,
                                                   __bf16* __restrict__ dst,
                                                   float* __restrict__ sqOut) {
  int tid = threadIdx.x;
  int row = blockIdx.x * 64 + (tid >> 2);
  int kg = tid & 3;
  int rb = row >> 7, rl = row & 127;
  int p1 = kg ^ (rl & 7);
  float sq = 0.f;
  #pragma unroll
  for (int kt = 0; kt < 8; kt++) {
    const float* s = src + (size_t)row * DIMS + kt * 32 + kg * 8;
    float4 u = *(const float4*)s;
    float4 v = *(const float4*)(s + 4);
    float f[8] = {u.x, u.y, u.z, u.w, v.x, v.y, v.z, v.w};
    bf16x8 hi, lo;
    #pragma unroll
    for (int e = 0; e < 8; e++) {
      __bf16 h = (__bf16)f[e];
      hi[e] = h;
      lo[e] = (__bf16)(f[e] - (float)h);
      sq = fmaf(f[e], f[e], sq);
    }
    size_t base = ((size_t)(rb * 8 + kt) * 128 + rl) * 64;
    *(bf16x8*)&dst[base + p1 * 8] = hi;
    *(bf16x8*)&dst[base + (p1 ^ 4) * 8] = lo;
  }
  sq += __shfl_xor(sq, 1);
  sq += __shfl_xor(sq, 2);
  if (kg == 0) sqOut[row] = sq;
}

// ---------- per-column sum / sumsq of W ----------
__global__ __launch_bounds__(256) void colstats_kernel(const float* __restrict__ W, float* ws) {
  int d = threadIdx.x;
  int r0 = blockIdx.x * 32;
  float s = 0.f, sq = 0.f;
  #pragma unroll 8
  for (int k = 0; k < 32; k++) {
    float v = W[(size_t)(r0 + k) * DIMS + d];
    s += v;
    sq = fmaf(v, v, sq);
  }
  atomicAdd(&ws[WS_COLSUM + d], s);
  atomicAdd(&ws[WS_COLSQ + d], sq);
}

// ---------- pass1: DMA-staged bf16-split MFMA distance GEMM ----------
// grid (8 ntile, 256 mtile), 256 threads = 4 waves in 2x2, 128x128 tile
__global__ __launch_bounds__(256) void pass1_kernel(const __bf16* __restrict__ Xp,
                                                    const __bf16* __restrict__ Wp,
                                                    float* ws) {
  __shared__ __align__(16) __bf16 Ab[128 * 64];  // 16 KB: [row][slot p][8]
  __shared__ __align__(16) __bf16 Bb[128 * 64];  // 16 KB
  __shared__ float wsqs[128];
  __shared__ float d1L[256];
  __shared__ float d2L[256];
  __shared__ int   i1L[256];

  int tid = threadIdx.x;
  int lane = tid & 63, wave = tid >> 6;
  int waveM = wave >> 1, waveN = wave & 1;
  int quad = lane >> 4, col = lane & 15;
  int bn = blockIdx.x, bm = blockIdx.y;
  int rowBase = bm * 128, cb = bn * 128;

  if (tid < 128) wsqs[tid] = ws[WS_WSQ + cb + tid];

  f32x4 acc[4][4];
  #pragma unroll
  for (int i = 0; i < 4; i++)
    #pragma unroll
    for (int j = 0; j < 4; j++) acc[i][j] = (f32x4){0.f, 0.f, 0.f, 0.f};

  for (int kt = 0; kt < 8; kt++) {
    const char* asrc = (const char*)(Xp + ((size_t)(bm * 8 + kt) << 13));
    const char* bsrc = (const char*)(Wp + ((size_t)(bn * 8 + kt) << 13));
    __syncthreads();  // previous iteration's fragment reads complete
    #pragma unroll
    for (int i = 0; i < 4; i++) {
      int off = wave * 4096 + i * 1024;
      gload_lds16(asrc + off + lane * 16, (char*)Ab + off);
      gload_lds16(bsrc + off + lane * 16, (char*)Bb + off);
    }
    __syncthreads();  // drains vmcnt -> LDS ready

    bf16x8 ah[4], al[4];
    #pragma unroll
    for (int mt = 0; mt < 4; mt++) {
      int r = waveM * 64 + mt * 16 + col;
      int ph = quad ^ (r & 7);
      ah[mt] = *(const bf16x8*)&Ab[r * 64 + ph * 8];
      al[mt] = *(const bf16x8*)&Ab[r * 64 + (ph ^ 4) * 8];
    }
    #pragma unroll
    for (int nt = 0; nt < 4; nt++) {
      int r = waveN * 64 + nt * 16 + col;
      int ph = quad ^ (r & 7);
      bf16x8 bh = *(const bf16x8*)&Bb[r * 64 + ph * 8];
      bf16x8 bl = *(const bf16x8*)&Bb[r * 64 + (ph ^ 4) * 8];
      #pragma unroll
      for (int mt = 0; mt < 4; mt++) {
        acc[mt][nt] = __builtin_amdgcn_mfma_f32_16x16x32_bf16(ah[mt], bh, acc[mt][nt], 0, 0, 0);
        acc[mt][nt] = __builtin_amdgcn_mfma_f32_16x16x32_bf16(ah[mt], bl, acc[mt][nt], 0, 0, 0);
        acc[mt][nt] = __builtin_amdgcn_mfma_f32_16x16x32_bf16(al[mt], bh, acc[mt][nt], 0, 0, 0);
      }
    }
  }

  // epilogue: per-row (best, 2nd, idx) over this block's 128 codes
  // C layout: row = quad*4 + reg, col = lane&15
  #pragma unroll
  for (int mt = 0; mt < 4; mt++) {
    #pragma unroll
    for (int r = 0; r < 4; r++) {
      float d1 = 3.0e38f, d2 = 3.0e38f;
      int i1 = 0;
      #pragma unroll
      for (int nt = 0; nt < 4; nt++) {
        int lc = waveN * 64 + nt * 16 + col;
        float d = wsqs[lc] - 2.0f * acc[mt][nt][r];
        int g = cb + lc;
        if (d < d1) { d2 = d1; d1 = d; i1 = g; }
        else if (d < d2) d2 = d;
      }
      #pragma unroll
      for (int m = 1; m < 16; m <<= 1) {
        float od1 = __shfl_xor(d1, m);
        int oi1 = __shfl_xor(i1, m);
        float od2 = __shfl_xor(d2, m);
        if (od1 < d1 || (od1 == d1 && oi1 < i1)) {
          d2 = fminf(d1, fminf(d2, od2));
          d1 = od1; i1 = oi1;
        } else {
          d2 = fminf(od1, fminf(d2, od2));
        }
      }
      if (col == 0) {
        int lr = waveM * 64 + mt * 16 + quad * 4 + r;
        d1L[lr * 2 + waveN] = d1;
        d2L[lr * 2 + waveN] = d2;
        i1L[lr * 2 + waveN] = i1;
      }
    }
  }
  __syncthreads();
  if (tid < 128) {
    float a1 = d1L[tid * 2], a2 = d2L[tid * 2];
    int ai = i1L[tid * 2];
    float b1 = d1L[tid * 2 + 1], b2 = d2L[tid * 2 + 1];
    int bi = i1L[tid * 2 + 1];
    float m1, m2; int mi;
    if (b1 < a1 || (b1 == a1 && bi < ai)) { m1 = b1; mi = bi; m2 = fminf(a1, b2); }
    else { m1 = a1; mi = ai; m2 = fminf(b1, a2); }
    int o = bn * NTOT + rowBase + tid;
    ws[WS_CAND1 + o] = m1;
    ws[WS_CAND2 + o] = m2;
    ((int*)ws)[WS_CANDI + o] = mi;
  }
}

// ---------- pass2: merge candidates; idx, commit, flags; fused quant gather ----------
__global__ __launch_bounds__(256) void pass2_kernel(const float* __restrict__ W,
                                                    float* __restrict__ outQ,
                                                    float* __restrict__ outIdx, float* ws) {
  __shared__ int idx_s[256];
  int tid = threadIdx.x;
  int row = blockIdx.x * 256 + tid;
  const float* c1 = ws + WS_CAND1;
  const float* c2 = ws + WS_CAND2;
  const int* ci = (const int*)ws + WS_CANDI;
  float m1 = 3.0e38f, m2 = 3.0e38f;
  int mi = 0;
  #pragma unroll
  for (int b = 0; b < 8; b++) {
    int o = b * NTOT + row;
    float b1 = c1[o], b2 = c2[o];
    int bi = ci[o];
    if (b1 < m1 || (b1 == m1 && bi < mi)) { m2 = fminf(m1, b2); m1 = b1; mi = bi; }
    else { m2 = fminf(m2, b1); }
  }
  outIdx[row] = (float)mi;
  idx_s[tid] = mi;
  int* wsI = (int*)ws;
  if (m2 - m1 < TAU) {
    int p = atomicAdd(&wsI[WS_FLAGCNT], 1);
    wsI[WS_FLAGS + p] = row;
  }
  float partial = ws[WS_XSQ + row] + m1;
  #pragma unroll
  for (int m = 32; m >= 1; m >>= 1) partial += __shfl_xor(partial, m);
  if ((tid & 63) == 0) atomicAdd(&ws[WS_COMMIT], partial);
  __syncthreads();
  int wave = tid >> 6, lane = tid & 63;
  int rowBase = blockIdx.x * 256;
  for (int i = 0; i < 64; i++) {
    int rl = wave * 64 + i;
    int ix = idx_s[rl];
    float4 v = ((const float4*)(W + (size_t)ix * DIMS))[lane];
    ((float4*)(outQ + (size_t)(rowBase + rl) * DIMS))[lane] = v;
  }
}

// ---------- decorrelation: block i computes cov(i,:) dots, squares, reduces ----------
__global__ __launch_bounds__(256) void cov_kernel(const float* __restrict__ W, float* ws) {
  __shared__ float wi_s[KCODES];
  __shared__ float red[4];
  int i = blockIdx.x, j = threadIdx.x;
  for (int t = j; t < KCODES; t += 256) wi_s[t] = W[(size_t)t * DIMS + i];
  __syncthreads();
  float a[8] = {0.f, 0.f, 0.f, 0.f, 0.f, 0.f, 0.f, 0.f};
  for (int k = 0; k < KCODES; k += 8) {
    #pragma unroll
    for (int u = 0; u < 8; u++)
      a[u] = fmaf(wi_s[k + u], W[(size_t)(k + u) * DIMS + j], a[u]);
  }
  float dot = ((a[0] + a[1]) + (a[2] + a[3])) + ((a[4] + a[5]) + (a[6] + a[7]));
  const float inv = 1.0f / 1024.0f;
  float mi = ws[WS_COLSUM + i] * inv, mj = ws[WS_COLSUM + j] * inv;
  float c = dot * inv - mi * mj;
  float v = (i == j) ? 0.0f : c * c;
  #pragma unroll
  for (int m = 32; m >= 1; m >>= 1) v += __shfl_xor(v, m);
  if ((j & 63) == 0) red[j >> 6] = v;
  __syncthreads();
  if (j == 0) atomicAdd(&ws[WS_DECORR], (red[0] + red[1]) + (red[2] + red[3]));
}

// ---------- f64 refinement of near-tie rows ----------
__global__ __launch_bounds__(256) void refine_kernel(const float* __restrict__ X,
                                                     const float* __restrict__ W,
                                                     float* __restrict__ outQ,
                                                     float* __restrict__ outIdx, float* ws) {
  __shared__ float xs[DIMS];
  __shared__ double dm[256];
  __shared__ int im[256];
  __shared__ int chosen;
  const int* wsI = (const int*)ws;
  int cnt = wsI[WS_FLAGCNT];
  const int* list = wsI + WS_FLAGS;
  int tid = threadIdx.x;
  for (int f = blockIdx.x; f < cnt; f += gridDim.x) {
    int row = list[f];
    __syncthreads();
    if (tid < 64) ((float4*)xs)[tid] = ((const float4*)(X + (size_t)row * DIMS))[tid];
    __syncthreads();
    double bd = 1.0e300;
    int bi = 0;
    for (int jj = 0; jj < 4; jj++) {
      int c = tid + 256 * jj;
      double a0 = 0.0, a1 = 0.0, a2 = 0.0, a3 = 0.0;
      const float* wr = W + (size_t)c * DIMS;
      #pragma unroll 4
      for (int d4 = 0; d4 < 64; d4++) {
        float4 w = ((const float4*)wr)[d4];
        float4 x = ((const float4*)xs)[d4];
        double e0 = (double)x.x - (double)w.x;
        double e1 = (double)x.y - (double)w.y;
        double e2 = (double)x.z - (double)w.z;
        double e3 = (double)x.w - (double)w.w;
        a0 += e0 * e0; a1 += e1 * e1; a2 += e2 * e2; a3 += e3 * e3;
      }
      double s = (a0 + a1) + (a2 + a3);
      if (s < bd) { bd = s; bi = c; }
    }
    dm[tid] = bd; im[tid] = bi;
    __syncthreads();
    for (int st = 128; st >= 1; st >>= 1) {
      if (tid < st) {
        if (dm[tid + st] < dm[tid] || (dm[tid + st] == dm[tid] && im[tid + st] < im[tid])) {
          dm[tid] = dm[tid + st]; im[tid] = im[tid + st];
        }
      }
      __syncthreads();
    }
    if (tid == 0) { chosen = im[0]; outIdx[row] = (float)im[0]; }
    __syncthreads();
    int ix = chosen;
    if (tid < 64)
      ((float4*)(outQ + (size_t)row * DIMS))[tid] = ((const float4*)(W + (size_t)ix * DIMS))[tid];
  }
}

// ---------- scalar losses ----------
__global__ __launch_bounds__(256) void finalize_kernel(const float* __restrict__ U, float* ws,
                                                       float* __restrict__ out) {
  __shared__ float red[256];
  int tid = threadIdx.x;
  float s = 0.f;
  for (int e = tid; e < KCODES; e += 256) s += U[e] + 1e-5f;
  red[tid] = s;
  __syncthreads();
  for (int st = 128; st >= 1; st >>= 1) {
    if (tid < st) red[tid] += red[tid + st];
    __syncthreads();
  }
  float S = red[0];
  __syncthreads();
  float denom = fmaxf(S, 1e-5f * 1024.0f);
  float h = 0.f;
  for (int e = tid; e < KCODES; e += 256) {
    float p = (U[e] + 1e-5f) / denom;
    h += p * logf(p + 1e-5f);
  }
  red[tid] = h;
  __syncthreads();
  for (int st = 128; st >= 1; st >>= 1) {
    if (tid < st) red[tid] += red[tid + st];
    __syncthreads();
  }
  float H = -red[0] / 6.93147180559945f;  // ln(1024)
  __syncthreads();
  float m = ws[WS_COLSUM + tid] * (1.0f / 1024.0f);
  float var = ws[WS_COLSQ + tid] * (1.0f / 1024.0f) - m * m;
  float r = 0.05f - var;
  red[tid] = r > 0.f ? r : 0.f;
  __syncthreads();
  for (int st = 128; st >= 1; st >>= 1) {
    if (tid < st) red[tid] += red[tid + st];
    __syncthreads();
  }
  if (tid == 0) {
    float varloss = 1e-3f * (red[0] / 256.0f);
    float gap = H < 0.5f ? (0.5f - H) : (H > 0.9f ? (H - 0.9f) : 0.0f);
    float entloss = 0.1f * gap * gap;
    float commit = 0.25f * ws[WS_COMMIT] / 8388608.0f;
    float dec = 1e-3f * ws[WS_DECORR] / 65536.0f;
    float* sc = out + OUT_SCAL;
    sc[0] = commit + entloss + varloss + dec;
    sc[1] = commit;
    sc[2] = entloss;
    sc[3] = varloss;
    sc[4] = dec;
    sc[5] = H;
  }
}

extern "C" void kernel_launch(void* const* d_in, const int* in_sizes, int n_in, void* d_out,
                              int out_size, void* d_ws, size_t ws_size, hipStream_t stream) {
  const float* X = (const float*)d_in[0];
  const float* W = (const float*)d_in[1];
  const float* U = (const float*)d_in[2];
  float* out = (float*)d_out;
  float* ws = (float*)d_ws;
  __bf16* Xp = (__bf16*)(out + OUT_Q);       // 33.55 MB, reused before gather overwrites
  __bf16* Wp = (__bf16*)(ws + WS_WP);        // 1 MB

  hipMemsetAsync(d_ws, 0, 2112, stream);
  pack_kernel<<<NTOT / 64, 256, 0, stream>>>(X, Xp, ws + WS_XSQ);
  pack_kernel<<<KCODES / 64, 256, 0, stream>>>(W, Wp, ws + WS_WSQ);
  colstats_kernel<<<32, 256, 0, stream>>>(W, ws);
  pass1_kernel<<<dim3(8, 256), 256, 0, stream>>>(Xp, Wp, ws);
  pass2_kernel<<<NTOT / 256, 256, 0, stream>>>(W, out + OUT_Q, out + OUT_IDX, ws);
  cov_kernel<<<256, 256, 0, stream>>>(W, ws);
  refine_kernel<<<512, 256, 0, stream>>>(X, W, out + OUT_Q, out + OUT_IDX, ws);
  finalize_kernel<<<1, 256, 0, stream>>>(U, ws, out);
}